// Round 1
// baseline (77.389 us; speedup 1.0000x reference)
//
#include <hip/hip_runtime.h>

// Problem constants (from reference):
#define T_DIM 1024
#define B_DIM 8
#define C_DIM 1024
#define H_DIM 16
#define K_SZ  7
#define P_PAD 3
#define O_DIM (H_DIM * K_SZ)   // 112
#define TB    (T_DIM * B_DIM)  // 8192 rows

#define BM 16    // rows per block in logit kernel
#define BK 128   // K-chunk staged in LDS

// Kernel 1: w = softmax_over_K( x @ W_lin^T + b_lin )
// Block: 256 threads = 16 rows x 16 heads. Each thread owns one (row, head):
// computes 7 logits (cols h*7..h*7+6), then softmax fully in-register.
__global__ __launch_bounds__(256) void logits_softmax_kernel(
    const float* __restrict__ x, const float* __restrict__ Wl,
    const float* __restrict__ bl, float* __restrict__ wout) {
  // +4 pad: keeps rows 16B-aligned for float4 LDS ops and breaks bank aliasing
  __shared__ float ws[O_DIM][BK + 4];
  const int tid = threadIdx.x;
  const int rg  = tid >> 4;     // row within block
  const int h   = tid & 15;     // head
  const int row = blockIdx.x * BM + rg;
  const float* __restrict__ xrow = x + (size_t)row * C_DIM;

  float acc[K_SZ];
#pragma unroll
  for (int j = 0; j < K_SZ; ++j) acc[j] = 0.f;

  for (int k0 = 0; k0 < C_DIM; k0 += BK) {
    __syncthreads();
    // stage W chunk: 112 x 128 floats = 3584 float4 = 14 per thread, coalesced
#pragma unroll
    for (int i = 0; i < (O_DIM * BK / 4) / 256; ++i) {
      int idx = tid + i * 256;
      int o   = idx >> 5;           // / (BK/4)
      int kk  = (idx & 31) << 2;
      float4 v = *reinterpret_cast<const float4*>(Wl + (size_t)o * C_DIM + k0 + kk);
      *reinterpret_cast<float4*>(&ws[o][kk]) = v;
    }
    __syncthreads();
#pragma unroll 4
    for (int kk = 0; kk < BK; kk += 4) {
      float4 xv = *reinterpret_cast<const float4*>(xrow + k0 + kk);
#pragma unroll
      for (int j = 0; j < K_SZ; ++j) {
        float4 wv = *reinterpret_cast<const float4*>(&ws[h * K_SZ + j][kk]);
        acc[j] += xv.x * wv.x;
        acc[j] += xv.y * wv.y;
        acc[j] += xv.z * wv.z;
        acc[j] += xv.w * wv.w;
      }
    }
  }

  // bias + softmax over the 7 kernel taps (all in-register)
  float m = -1e30f;
#pragma unroll
  for (int j = 0; j < K_SZ; ++j) {
    acc[j] += bl[h * K_SZ + j];
    m = fmaxf(m, acc[j]);
  }
  float s = 0.f;
#pragma unroll
  for (int j = 0; j < K_SZ; ++j) {
    acc[j] = __expf(acc[j] - m);
    s += acc[j];
  }
  float inv = 1.0f / s;
  float* wp = wout + (size_t)row * O_DIM + h * K_SZ;
#pragma unroll
  for (int j = 0; j < K_SZ; ++j) wp[j] = acc[j] * inv;
}

// Kernel 2: out[t,b,c] = sum_j w[t,b,h(c),j] * x[t-3+j, b, c] + bias[c]
// One block per (t,b) row; thread handles 4 consecutive channels (float4).
__global__ __launch_bounds__(256) void dynconv_kernel(
    const float* __restrict__ x, const float* __restrict__ w,
    const float* __restrict__ bias, float* __restrict__ out) {
  const int row = blockIdx.x;   // t*B + b
  const int t   = row >> 3;
  const int b   = row & 7;
  const int tid = threadIdx.x;
  const int c4  = tid << 2;     // channel base
  const int h   = c4 >> 6;      // head (R = 64 channels per head)
  const float* __restrict__ wr = w + (size_t)row * O_DIM + h * K_SZ;

  float ax = 0.f, ay = 0.f, az = 0.f, aw = 0.f;
#pragma unroll
  for (int j = 0; j < K_SZ; ++j) {
    int st = t - P_PAD + j;
    if (st < 0 || st >= T_DIM) continue;   // uniform branch per block
    float wj = wr[j];
    const float4 xv = *reinterpret_cast<const float4*>(
        x + ((size_t)(st * B_DIM + b)) * C_DIM + c4);
    ax += wj * xv.x;
    ay += wj * xv.y;
    az += wj * xv.z;
    aw += wj * xv.w;
  }
  float4 bv = *reinterpret_cast<const float4*>(bias + c4);
  float4 o4 = make_float4(ax + bv.x, ay + bv.y, az + bv.z, aw + bv.w);
  *reinterpret_cast<float4*>(out + (size_t)row * C_DIM + c4) = o4;
}

extern "C" void kernel_launch(void* const* d_in, const int* in_sizes, int n_in,
                              void* d_out, int out_size, void* d_ws, size_t ws_size,
                              hipStream_t stream) {
  const float* x  = (const float*)d_in[0];   // (T,B,C)
  const float* Wl = (const float*)d_in[1];   // (H*K, C)
  const float* bl = (const float*)d_in[2];   // (H*K,)
  const float* cb = (const float*)d_in[3];   // (C,)
  float* out  = (float*)d_out;               // (T,B,C)
  float* wbuf = (float*)d_ws;                // (TB, O_DIM) softmax weights

  logits_softmax_kernel<<<TB / BM, 256, 0, stream>>>(x, Wl, bl, wbuf);
  dynconv_kernel<<<TB, 256, 0, stream>>>(x, wbuf, cb, out);
}

// Round 2
// 43.104 us; speedup vs baseline: 1.7954x; 1.7954x over previous
//
#include <hip/hip_runtime.h>
#include <stdint.h>

// Problem constants (from reference):
#define T_DIM 1024
#define B_DIM 8
#define C_DIM 1024
#define H_DIM 16
#define K_SZ  7
#define P_PAD 3
#define O_DIM (H_DIM * K_SZ)   // 112
#define TB    (T_DIM * B_DIM)  // 8192 rows

typedef __attribute__((ext_vector_type(8))) short bf16x8;  // 4 VGPRs, 8 bf16
typedef __attribute__((ext_vector_type(4))) float f32x4;

union FragU { uint32_t u[4]; bf16x8 v; };

// RNE fp32->bf16 pack of two floats into one dword (lo=a, hi=b)
__device__ inline uint32_t pk_bf16(float a, float b) {
  uint32_t ua = __float_as_uint(a), ub = __float_as_uint(b);
  ua += 0x7FFFu + ((ua >> 16) & 1u);
  ub += 0x7FFFu + ((ub >> 16) & 1u);
  return (ua >> 16) | (ub & 0xFFFF0000u);
}

// Load 8 consecutive fp32 and convert to a bf16x8 MFMA fragment slice.
// k-ordering is identical for A and B loads, so any internal permutation
// cancels in the dot product.
__device__ inline bf16x8 load_bf16x8(const float* __restrict__ p) {
  float4 lo = *reinterpret_cast<const float4*>(p);
  float4 hi = *reinterpret_cast<const float4*>(p + 4);
  FragU f;
  f.u[0] = pk_bf16(lo.x, lo.y);
  f.u[1] = pk_bf16(lo.z, lo.w);
  f.u[2] = pk_bf16(hi.x, hi.y);
  f.u[3] = pk_bf16(hi.z, hi.w);
  return f.v;
}

// Kernel 1: w = softmax_over_K( x @ W_lin^T + b_lin ) via bf16 MFMA.
// Block: 256 threads = 4 waves. Block tile = 32 rows x 112 cols.
// Waves K-split (256 each), partials reduced through LDS, softmax fused.
__global__ __launch_bounds__(256) void logits_mfma_kernel(
    const float* __restrict__ x, const float* __restrict__ Wl,
    const float* __restrict__ bl, float* __restrict__ wout) {
  // [wave][row32][col112 padded->116]: 4*32*116*4 = 59392 B
  // pad 112->116: 4-row stride = 464B, not bank-aligned -> no 4-way conflict
  __shared__ float part[4][32][116];

  const int tid  = threadIdx.x;
  const int wv   = tid >> 6;
  const int lane = tid & 63;
  const int l15  = lane & 15;
  const int oct  = lane >> 4;
  const int rb   = blockIdx.x * 32;   // 8192/32 = 256 blocks

  f32x4 acc[2][7];
#pragma unroll
  for (int mf = 0; mf < 2; ++mf)
#pragma unroll
    for (int nf = 0; nf < 7; ++nf)
      acc[mf][nf] = (f32x4)(0.f);

  const int kw = wv * 256;            // this wave's K range
  const float* __restrict__ xp0 = x  + (size_t)(rb + l15) * C_DIM + kw + oct * 8;
  const float* __restrict__ xp1 = xp0 + (size_t)16 * C_DIM;
  const float* __restrict__ wp  = Wl + (size_t)l15 * C_DIM + kw + oct * 8;

#pragma unroll
  for (int s = 0; s < 8; ++s) {
    const int ko = s * 32;
    bf16x8 a0 = load_bf16x8(xp0 + ko);
    bf16x8 a1 = load_bf16x8(xp1 + ko);
#pragma unroll
    for (int nf = 0; nf < 7; ++nf) {
      bf16x8 b = load_bf16x8(wp + (size_t)(nf * 16) * C_DIM + ko);
      acc[0][nf] = __builtin_amdgcn_mfma_f32_16x16x32_bf16(a0, b, acc[0][nf], 0, 0, 0);
      acc[1][nf] = __builtin_amdgcn_mfma_f32_16x16x32_bf16(a1, b, acc[1][nf], 0, 0, 0);
    }
  }

  // D layout (guide-verified): col = lane&15, row = (lane>>4)*4 + reg
#pragma unroll
  for (int mf = 0; mf < 2; ++mf)
#pragma unroll
    for (int nf = 0; nf < 7; ++nf)
#pragma unroll
      for (int r = 0; r < 4; ++r)
        part[wv][mf * 16 + oct * 4 + r][nf * 16 + l15] = acc[mf][nf][r];

  __syncthreads();

  // Reduce 4 K-partials + bias + softmax over the 7 taps.
  // 512 (row, head) pairs, 2 per thread; softmax fully in-register.
#pragma unroll
  for (int p = tid; p < 512; p += 256) {
    const int row = p >> 4;
    const int h   = p & 15;
    float lg[7];
    float m = -1e30f;
#pragma unroll
    for (int j = 0; j < 7; ++j) {
      const int c = h * 7 + j;
      float sum = part[0][row][c] + part[1][row][c]
                + part[2][row][c] + part[3][row][c] + bl[c];
      lg[j] = sum;
      m = fmaxf(m, sum);
    }
    float s = 0.f;
#pragma unroll
    for (int j = 0; j < 7; ++j) { lg[j] = __expf(lg[j] - m); s += lg[j]; }
    const float inv = 1.0f / s;
    float* __restrict__ op = wout + (size_t)(rb + row) * O_DIM + h * 7;
#pragma unroll
    for (int j = 0; j < 7; ++j) op[j] = lg[j] * inv;
  }
}

// Kernel 2: out[t,b,c] = sum_j w[t,b,h(c),j] * x[t-3+j, b, c] + bias[c]
// One block per (t,b) row; thread handles 4 consecutive channels (float4).
__global__ __launch_bounds__(256) void dynconv_kernel(
    const float* __restrict__ x, const float* __restrict__ w,
    const float* __restrict__ bias, float* __restrict__ out) {
  const int row = blockIdx.x;   // t*B + b
  const int t   = row >> 3;
  const int b   = row & 7;
  const int tid = threadIdx.x;
  const int c4  = tid << 2;     // channel base
  const int h   = c4 >> 6;      // head (R = 64 channels per head)
  const float* __restrict__ wr = w + (size_t)row * O_DIM + h * K_SZ;

  float ax = 0.f, ay = 0.f, az = 0.f, aw = 0.f;
#pragma unroll
  for (int j = 0; j < K_SZ; ++j) {
    int st = t - P_PAD + j;
    if (st < 0 || st >= T_DIM) continue;   // uniform branch per block
    float wj = wr[j];
    const float4 xv = *reinterpret_cast<const float4*>(
        x + ((size_t)(st * B_DIM + b)) * C_DIM + c4);
    ax += wj * xv.x;
    ay += wj * xv.y;
    az += wj * xv.z;
    aw += wj * xv.w;
  }
  float4 bv = *reinterpret_cast<const float4*>(bias + c4);
  float4 o4 = make_float4(ax + bv.x, ay + bv.y, az + bv.z, aw + bv.w);
  *reinterpret_cast<float4*>(out + (size_t)row * C_DIM + c4) = o4;
}

extern "C" void kernel_launch(void* const* d_in, const int* in_sizes, int n_in,
                              void* d_out, int out_size, void* d_ws, size_t ws_size,
                              hipStream_t stream) {
  const float* x  = (const float*)d_in[0];   // (T,B,C)
  const float* Wl = (const float*)d_in[1];   // (H*K, C)
  const float* bl = (const float*)d_in[2];   // (H*K,)
  const float* cb = (const float*)d_in[3];   // (C,)
  float* out  = (float*)d_out;               // (T,B,C)
  float* wbuf = (float*)d_ws;                // (TB, O_DIM) softmax weights

  logits_mfma_kernel<<<TB / 32, 256, 0, stream>>>(x, Wl, bl, wbuf);
  dynconv_kernel<<<TB, 256, 0, stream>>>(x, wbuf, cb, out);
}